// Round 11
// baseline (213.909 us; speedup 1.0000x reference)
//
#include <hip/hip_runtime.h>

#define N_NODES 32768
#define N_EDGES 16384
#define DEG 4
#define KPE 8
#define DIM 128
#define EDIM 64

// per-wave attn LDS region: K(32x272) + P(8x36 f32)
#define AOFF_K 0
#define AOFF_P 8704
#define AWAVESZ 9856

typedef float f32x4 __attribute__((ext_vector_type(4)));
typedef __bf16 bf16x8 __attribute__((ext_vector_type(8)));
typedef __bf16 bf16x2 __attribute__((ext_vector_type(2)));
typedef unsigned short u16x8 __attribute__((ext_vector_type(8)));
typedef unsigned int u32;
typedef unsigned int u32x4 __attribute__((ext_vector_type(4)));

static __device__ __forceinline__ unsigned short f2bf(float f) {
  union { float f; unsigned int u; } v; v.f = f;
  unsigned int r = (v.u + 0x7FFFu + ((v.u >> 16) & 1u)) >> 16;
  return (unsigned short)r;
}
static __device__ __forceinline__ float bflo(unsigned int v) {
  union { unsigned int u; float f; } x; x.u = v << 16; return x.f;
}
static __device__ __forceinline__ float bfhi(unsigned int v) {
  union { unsigned int u; float f; } x; x.u = v & 0xffff0000u; return x.f;
}

#if __has_builtin(__builtin_amdgcn_fdot2_f32_bf16)
static __device__ __forceinline__ float dot2bf(unsigned int a, unsigned int b, float c) {
  return __builtin_amdgcn_fdot2_f32_bf16(
      __builtin_bit_cast(bf16x2, a), __builtin_bit_cast(bf16x2, b), c, false);
}
#else
static __device__ __forceinline__ float dot2bf(unsigned int a, unsigned int b, float c) {
  c = fmaf(bflo(a), bflo(b), c);
  return fmaf(bfhi(a), bfhi(b), c);
}
#endif

// ---------------- wprep ----------------
__global__ __launch_bounds__(256) void wprep_kernel(
    const float* __restrict__ Wq, const float* __restrict__ Wk,
    const float* __restrict__ Wv, const float* __restrict__ Wlin,
    const float* __restrict__ Wedge, const float* __restrict__ Wo,
    unsigned short* __restrict__ CW, unsigned short* __restrict__ CWE,
    unsigned short* __restrict__ Wob)
{
  int id = blockIdx.x * 256 + threadIdx.x;
  if (id < 384 * 128) {
    int j = id >> 7, i = id & 127;
    const float* wrow; float scale = 1.0f;
    if (j < 128)      { wrow = Wq + j * 128; scale = 0.25f; }
    else if (j < 256) { wrow = Wk + (j - 128) * 128; }
    else              { wrow = Wv + (j - 256) * 128; }
    float s = 0.f;
    #pragma unroll 8
    for (int m = 0; m < 128; ++m) s += wrow[m] * Wlin[m * 128 + i];
    CW[id] = f2bf(s * scale);
  } else if (id < 384 * 128 + 128 * 64) {
    int id2 = id - 384 * 128; int j = id2 >> 6, t = id2 & 63;
    float s = 0.f;
    #pragma unroll 8
    for (int m = 0; m < 128; ++m) s += Wk[j * 128 + m] * Wedge[m * 64 + t];
    CWE[id2] = f2bf(s);
  } else if (id < 384 * 128 + 128 * 64 + 128 * 128) {
    int id3 = id - (384 * 128 + 128 * 64);
    Wob[id3] = f2bf(Wo[id3]);
  }
}

// ---------------- g12: x -> q/K/V tables;  ea -> WeK table ----------------
__global__ __launch_bounds__(256) void g12_kernel(
    const float* __restrict__ x, const unsigned short* __restrict__ CW,
    const float* __restrict__ bq, const float* __restrict__ bv,
    unsigned short* __restrict__ qb, unsigned short* __restrict__ Kb,
    unsigned short* __restrict__ Vb,
    const float* __restrict__ ea, const unsigned short* __restrict__ CWE,
    const float* __restrict__ bk, unsigned short* __restrict__ WeKb)
{
  const int wave = threadIdx.x >> 6, lane = threadIdx.x & 63;
  const int r16 = lane & 15, quad = lane >> 4;
  const int unit = blockIdx.x;

  if (unit < 512) {
    const int m0 = unit * 64 + wave * 16;
    u16x8 av[4];
    const float* arow = x + (size_t)(m0 + r16) * DIM + quad * 8;
    #pragma unroll
    for (int kk = 0; kk < 4; ++kk) {
      float4 a0 = *(const float4*)(arow + kk * 32);
      float4 a1 = *(const float4*)(arow + kk * 32 + 4);
      u16x8 au;
      au[0] = f2bf(a0.x); au[1] = f2bf(a0.y); au[2] = f2bf(a0.z); au[3] = f2bf(a0.w);
      au[4] = f2bf(a1.x); au[5] = f2bf(a1.y); au[6] = f2bf(a1.z); au[7] = f2bf(a1.w);
      av[kk] = au;
    }
    #pragma unroll
    for (int g = 0; g < 6; ++g) {
      f32x4 acc[4];
      const f32x4 z = {0.f, 0.f, 0.f, 0.f};
      acc[0] = z; acc[1] = z; acc[2] = z; acc[3] = z;
      #pragma unroll
      for (int kk = 0; kk < 4; ++kk) {
        #pragma unroll
        for (int s = 0; s < 4; ++s) {
          u16x8 bu = *(const u16x8*)(CW + (size_t)(g * 64 + s * 16 + r16) * DIM + kk * 32 + quad * 8);
          acc[s] = __builtin_amdgcn_mfma_f32_16x16x32_bf16(
              __builtin_bit_cast(bf16x8, av[kk]), __builtin_bit_cast(bf16x8, bu), acc[s], 0, 0, 0);
        }
      }
      const int arr = g >> 1;               // 0:q 1:K 2:V
      const int colbase = (g & 1) * 64;
      unsigned short* dst = arr == 0 ? qb : (arr == 1 ? Kb : Vb);
      #pragma unroll
      for (int s = 0; s < 4; ++s) {
        int j = colbase + s * 16 + r16;
        float bias = arr == 0 ? 0.25f * bq[j] : (arr == 2 ? bv[j] : 0.f);
        #pragma unroll
        for (int r = 0; r < 4; ++r) {
          int m = m0 + quad * 4 + r;
          dst[(size_t)m * DIM + j] = f2bf(acc[s][r] + bias);
        }
      }
    }
  } else {
    const int idx = unit - 512;
    const int m0 = (idx >> 1) * 64 + wave * 16;
    const int n0 = (idx & 1) * 64;
    f32x4 acc[4];
    const f32x4 z = {0.f, 0.f, 0.f, 0.f};
    acc[0] = z; acc[1] = z; acc[2] = z; acc[3] = z;
    const float* arow = ea + (size_t)(m0 + r16) * EDIM + quad * 8;
    #pragma unroll
    for (int kk = 0; kk < 2; ++kk) {
      float4 a0 = *(const float4*)(arow + kk * 32);
      float4 a1 = *(const float4*)(arow + kk * 32 + 4);
      u16x8 au;
      au[0] = f2bf(a0.x); au[1] = f2bf(a0.y); au[2] = f2bf(a0.z); au[3] = f2bf(a0.w);
      au[4] = f2bf(a1.x); au[5] = f2bf(a1.y); au[6] = f2bf(a1.z); au[7] = f2bf(a1.w);
      bf16x8 av = __builtin_bit_cast(bf16x8, au);
      #pragma unroll
      for (int s = 0; s < 4; ++s) {
        u16x8 bu = *(const u16x8*)(CWE + (size_t)(n0 + s * 16 + r16) * EDIM + kk * 32 + quad * 8);
        acc[s] = __builtin_amdgcn_mfma_f32_16x16x32_bf16(
            av, __builtin_bit_cast(bf16x8, bu), acc[s], 0, 0, 0);
      }
    }
    #pragma unroll
    for (int s = 0; s < 4; ++s) {
      int j = n0 + s * 16 + r16;
      float bias = bk[j];
      #pragma unroll
      for (int r = 0; r < 4; ++r) {
        int m = m0 + quad * 4 + r;
        WeKb[(size_t)m * DIM + j] = f2bf(acc[s][r] + bias);
      }
    }
  }
}

// ---------------- ktab: KeyTab[e*8+j] = bf16(Kb[enodes[e][j]] + WeKb[e]) ------
// 131072 contiguous rows; each wave does 16 rows (coalesced 256 B per row).
// Fully occupancy-bound memory kernel (~67 MB moved).
__global__ __launch_bounds__(256) void ktab_kernel(
    const unsigned short* __restrict__ Kb, const unsigned short* __restrict__ WeKb,
    const int* __restrict__ enodes, unsigned short* __restrict__ KT)
{
  const int wave = threadIdx.x >> 6, lane = threadIdx.x & 63;
  const int r0 = (blockIdx.x * 4 + wave) * 16;
  #pragma unroll
  for (int t = 0; t < 16; ++t) {
    const int r = r0 + t;
    const int u = enodes[r];       // wave-uniform (row index == flat enodes idx)
    const int e = r >> 3;
    u32 kv = *(const u32*)(Kb + (size_t)u * DIM + lane * 2);
    u32 ev = *(const u32*)(WeKb + (size_t)e * DIM + lane * 2);
    float lo = bflo(kv) + bflo(ev);
    float hi = bfhi(kv) + bfhi(ev);
    u32 pk = (u32)f2bf(lo) | ((u32)f2bf(hi) << 16);
    *(u32*)(KT + (size_t)r * DIM + lane * 2) = pk;
  }
}

// ---------------- attn: KeyTab rows contiguous per edge ----------------
// Per node: 8 coalesced 1 KB KeyTab loads -> regs -> 8 ds_write_b128 into the
// proven stride-272 LDS layout (r10: 0 bank conflicts). Scores are 32 dot2
// (e-add pre-folded in KeyTab). V gathers (32 coalesced 4 B wave-reads) stay
// in flight under scores+softmax via the r10 fence pipeline.
__global__ __launch_bounds__(256, 3) void attn_kernel(
    const unsigned short* __restrict__ qb, const unsigned short* __restrict__ KT,
    const unsigned short* __restrict__ Vb,
    const int* __restrict__ nedges, const int* __restrict__ enodes,
    unsigned short* __restrict__ ctxb)
{
  __shared__ __align__(16) unsigned char slds[AWAVESZ * 4];
  const int wave = threadIdx.x >> 6, lane = threadIdx.x & 63;
  unsigned char* abuf = slds + wave * AWAVESZ;
  float* ldsP = (float*)(abuf + AOFF_P);
  const int n = blockIdx.x * 4 + wave;
  const int l = lane & 31, half = lane >> 5;
  const int h = lane >> 3;
  const int c0 = lane * 2;

  int4 e4 = *(const int4*)(nedges + (size_t)n * DEG);
  int4 m0i = *(const int4*)(enodes + (size_t)e4.x * KPE);
  int4 m1i = *(const int4*)(enodes + (size_t)e4.x * KPE + 4);
  int4 m2i = *(const int4*)(enodes + (size_t)e4.y * KPE);
  int4 m3i = *(const int4*)(enodes + (size_t)e4.y * KPE + 4);
  int4 m4i = *(const int4*)(enodes + (size_t)e4.z * KPE);
  int4 m5i = *(const int4*)(enodes + (size_t)e4.z * KPE + 4);
  int4 m6i = *(const int4*)(enodes + (size_t)e4.w * KPE);
  int4 m7i = *(const int4*)(enodes + (size_t)e4.w * KPE + 4);

  // q (wave-uniform row, nontemporal): oldest VMEM after idx
  const u32x4* qp = (const u32x4*)(qb + (size_t)n * DIM + half * 64);
  u32x4 qv[8];
  #pragma unroll
  for (int ch = 0; ch < 8; ++ch) qv[ch] = __builtin_nontemporal_load(qp + ch);

  // KeyTab loads: 8 coalesced 1 KB reads (4 rows each)
  u32x4 kt[8];
#define KTLOAD(i, e, sub) kt[i] = *(const u32x4*)(KT + ((size_t)(e) * 8 + (sub)) * DIM + lane * 8)
  KTLOAD(0, e4.x, 0); KTLOAD(1, e4.x, 4);
  KTLOAD(2, e4.y, 0); KTLOAD(3, e4.y, 4);
  KTLOAD(4, e4.z, 0); KTLOAD(5, e4.z, 4);
  KTLOAD(6, e4.w, 0); KTLOAD(7, e4.w, 4);
#undef KTLOAD

  // Fence: pins q+kt issue before V issue (keeps the vmcnt(32) math exact).
  asm volatile("" ::: "memory");

  // V rows (coalesced 256 B wave reads): youngest 32 VMEM ops
  u32 vv[32];
#define VLOAD(t, row) vv[t] = *(const u32*)(Vb + (size_t)(row) * DIM + c0)
  VLOAD(0,  m0i.x); VLOAD(1,  m0i.y); VLOAD(2,  m0i.z); VLOAD(3,  m0i.w);
  VLOAD(4,  m1i.x); VLOAD(5,  m1i.y); VLOAD(6,  m1i.z); VLOAD(7,  m1i.w);
  VLOAD(8,  m2i.x); VLOAD(9,  m2i.y); VLOAD(10, m2i.z); VLOAD(11, m2i.w);
  VLOAD(12, m3i.x); VLOAD(13, m3i.y); VLOAD(14, m3i.z); VLOAD(15, m3i.w);
  VLOAD(16, m4i.x); VLOAD(17, m4i.y); VLOAD(18, m4i.z); VLOAD(19, m4i.w);
  VLOAD(20, m5i.x); VLOAD(21, m5i.y); VLOAD(22, m5i.z); VLOAD(23, m5i.w);
  VLOAD(24, m6i.x); VLOAD(25, m6i.y); VLOAD(26, m6i.z); VLOAD(27, m6i.w);
  VLOAD(28, m7i.x); VLOAD(29, m7i.y); VLOAD(30, m7i.z); VLOAD(31, m7i.w);
#undef VLOAD

  // Drain q+kt (and idx); leave the 32 V loads in flight under compute.
  asm volatile("s_waitcnt vmcnt(32)" ::: "memory");

  // kt -> LDS, padded stride 272 (instr i covers rows i*4..i*4+3)
  {
    const int wr = lane >> 4, wc = lane & 15;
    #pragma unroll
    for (int i = 0; i < 8; ++i)
      *(u32x4*)(abuf + AOFF_K + (size_t)(i * 4 + wr) * 272 + wc * 16) = kt[i];
  }

  // scores: s[hi] = q . KeyTab-row(l) over this half's 64 dims (32 dot2)
  const unsigned char* krow = abuf + AOFF_K + l * 272 + half * 128;
  float s[4] = {0.f, 0.f, 0.f, 0.f};
  #pragma unroll
  for (int ch = 0; ch < 8; ++ch) {
    uint4 kc = *(const uint4*)(krow + ch * 16);
    const int hi = ch >> 1;
    float t = s[hi];
    t = dot2bf(qv[ch].x, kc.x, t);
    t = dot2bf(qv[ch].y, kc.y, t);
    t = dot2bf(qv[ch].z, kc.z, t);
    t = dot2bf(qv[ch].w, kc.w, t);
    s[hi] = t;
  }

  // softmax over the 32 keys (within each 32-lane half-group)
  #pragma unroll
  for (int hi = 0; hi < 4; ++hi) {
    float vmax = s[hi];
    #pragma unroll
    for (int off = 16; off >= 1; off >>= 1)
      vmax = fmaxf(vmax, __shfl_xor(vmax, off, 32));
    float ex = __expf(s[hi] - vmax);
    float sum = ex;
    #pragma unroll
    for (int off = 16; off >= 1; off >>= 1)
      sum += __shfl_xor(sum, off, 32);
    ldsP[(half * 4 + hi) * 36 + l] = ex / sum;
  }

  // ctx: lane = dim pair; V regs (compiler waits precisely), P via LDS
  float a0 = 0.f, a1 = 0.f;
  #pragma unroll
  for (int t = 0; t < 8; ++t) {
    float4 p4 = *(const float4*)(ldsP + h * 36 + t * 4);
    a0 = fmaf(p4.x, bflo(vv[t * 4 + 0]), a0); a1 = fmaf(p4.x, bfhi(vv[t * 4 + 0]), a1);
    a0 = fmaf(p4.y, bflo(vv[t * 4 + 1]), a0); a1 = fmaf(p4.y, bfhi(vv[t * 4 + 1]), a1);
    a0 = fmaf(p4.z, bflo(vv[t * 4 + 2]), a0); a1 = fmaf(p4.z, bfhi(vv[t * 4 + 2]), a1);
    a0 = fmaf(p4.w, bflo(vv[t * 4 + 3]), a0); a1 = fmaf(p4.w, bfhi(vv[t * 4 + 3]), a1);
  }
  unsigned int pk = (unsigned int)f2bf(a0) | ((unsigned int)f2bf(a1) << 16);
  __builtin_nontemporal_store(pk, (u32*)(ctxb + (size_t)n * DIM + c0));
}

// ---------------- g4: ctx @ Wo^T + bo, ReLU -> out fp32 ----------------
__global__ __launch_bounds__(256) void g4_kernel(
    const unsigned short* __restrict__ ctxb, const unsigned short* __restrict__ Wob,
    const float* __restrict__ bo, float* __restrict__ out)
{
  const int wave = threadIdx.x >> 6, lane = threadIdx.x & 63;
  const int r16 = lane & 15, quad = lane >> 4;
  const int bx = blockIdx.x & 511, by = blockIdx.x >> 9;
  const int m0 = bx * 64 + wave * 16;
  const int n0 = by * 64;
  f32x4 acc[4];
  const f32x4 z = {0.f, 0.f, 0.f, 0.f};
  acc[0] = z; acc[1] = z; acc[2] = z; acc[3] = z;
  #pragma unroll
  for (int kk = 0; kk < 4; ++kk) {
    u16x8 au = *(const u16x8*)(ctxb + (size_t)(m0 + r16) * DIM + kk * 32 + quad * 8);
    bf16x8 av = __builtin_bit_cast(bf16x8, au);
    #pragma unroll
    for (int s = 0; s < 4; ++s) {
      u16x8 bu = *(const u16x8*)(Wob + (size_t)(n0 + s * 16 + r16) * DIM + kk * 32 + quad * 8);
      acc[s] = __builtin_amdgcn_mfma_f32_16x16x32_bf16(
          av, __builtin_bit_cast(bf16x8, bu), acc[s], 0, 0, 0);
    }
  }
  #pragma unroll
  for (int s = 0; s < 4; ++s) {
    int j = n0 + s * 16 + r16;
    float bias = bo[j];
    #pragma unroll
    for (int r = 0; r < 4; ++r) {
      int m = m0 + quad * 4 + r;
      float v = acc[s][r] + bias;
      out[(size_t)m * DIM + j] = v > 0.f ? v : 0.f;
    }
  }
}

extern "C" void kernel_launch(void* const* d_in, const int* in_sizes, int n_in,
                              void* d_out, int out_size, void* d_ws, size_t ws_size,
                              hipStream_t stream)
{
  const float* x     = (const float*)d_in[0];
  const float* ea    = (const float*)d_in[1];
  const int* nedges  = (const int*)d_in[2];
  const int* enodes  = (const int*)d_in[3];
  const float* Wlin  = (const float*)d_in[4];
  const float* Wedge = (const float*)d_in[5];
  const float* Wq    = (const float*)d_in[6];
  const float* Wk    = (const float*)d_in[7];
  const float* Wv    = (const float*)d_in[8];
  const float* bq    = (const float*)d_in[9];
  const float* bk    = (const float*)d_in[10];
  const float* bv    = (const float*)d_in[11];
  const float* Wo    = (const float*)d_in[12];
  const float* bo    = (const float*)d_in[13];
  float* out = (float*)d_out;

  unsigned short* wsp = (unsigned short*)d_ws;
  unsigned short* CW   = wsp;  wsp += 384 * 128;
  unsigned short* CWE  = wsp;  wsp += 128 * 64;
  unsigned short* Wob  = wsp;  wsp += 128 * 128;
  unsigned short* qb   = wsp;  wsp += (size_t)N_NODES * DIM;
  unsigned short* Kb   = wsp;  wsp += (size_t)N_NODES * DIM;
  unsigned short* Vb   = wsp;  wsp += (size_t)N_NODES * DIM;
  unsigned short* WeKb = wsp;  wsp += (size_t)N_EDGES * DIM;
  unsigned short* ctxb = wsp;  wsp += (size_t)N_NODES * DIM;
  unsigned short* KT   = wsp;  wsp += (size_t)N_EDGES * KPE * DIM;  // 33.6 MB

  wprep_kernel<<<dim3(288), dim3(256), 0, stream>>>(Wq, Wk, Wv, Wlin, Wedge, Wo, CW, CWE, Wob);
  g12_kernel<<<dim3(1024), dim3(256), 0, stream>>>(x, CW, bq, bv, qb, Kb, Vb, ea, CWE, bk, WeKb);
  ktab_kernel<<<dim3(2048), dim3(256), 0, stream>>>(Kb, WeKb, enodes, KT);
  attn_kernel<<<dim3(8192), dim3(256), 0, stream>>>(qb, KT, Vb, nedges, enodes, ctxb);
  g4_kernel<<<dim3(1024), dim3(256), 0, stream>>>(ctxb, Wob, bo, out);
}